// Round 10
// baseline (3330.055 us; speedup 1.0000x reference)
//
#include <hip/hip_runtime.h>
#include <math.h>

#define BB 4
#define NP 8192
#define CF 64
#define MQ 2048
#define KS 32

// ---- workspace layout (float indices) ----
#define WS_FT     0u
#define WS_NIDX   2097152u
#define WS_IDXI   2359296u
#define WS_ST1    2367488u
#define WS_ST2    2375680u
#define WS_SC1    2392064u
#define WS_SC2    2392192u
#define WS_MAXY2  2392448u
#define WS_W1P    3441024u

typedef float v2f __attribute__((ext_vector_type(2)));
typedef unsigned long long u64;

// ------------------------------------------------------------------
// transpose f [B][64][N] -> ft [B][N][64]
// ------------------------------------------------------------------
__global__ __launch_bounds__(256) void transpose_f_kernel(
    const float* __restrict__ f, float* __restrict__ ft) {
  __shared__ float tile[64][65];
  int b = blockIdx.y;
  int n0 = blockIdx.x * 64;
  int cc = threadIdx.x >> 6;
  int nn = threadIdx.x & 63;
  #pragma unroll
  for (int r = 0; r < 16; ++r) {
    int c = cc * 16 + r;
    tile[c][nn] = f[((size_t)b * 64 + c) * NP + n0 + nn];
  }
  __syncthreads();
  #pragma unroll
  for (int r = 0; r < 16; ++r) {
    int nl = cc * 16 + r;
    ft[((size_t)b * NP + n0 + nl) * 64 + nn] = tile[nn][nl];
  }
}

// ------------------------------------------------------------------
__global__ void prep_w1_kernel(const float* __restrict__ w1, float* __restrict__ w1p) {
  int i = blockIdx.x * 256 + threadIdx.x;
  if (i < 64 * 68) {
    int o = i / 68, c = i % 68;
    w1p[i] = (c < 67) ? w1[o * 67 + c] : 0.0f;
  }
}

// ------------------------------------------------------------------
// FPS v9: 256 threads (r6's proven cheap 4-wave tail: triple-buffered
// cnd atomicMax + ONE barrier/iter) + GROUP-GRANULAR pruning with
// UNIFORM branches (the r8 lesson: per-lane exec-masked pruning can't
// cut a dirty wave's issue; 8-wave sync fan-in costs ~1700cy tail).
// Deterministic counting sort (r8's ballot-leader scatter, 8-bit
// interleaved cells) makes v2f group k of wave w = 128 CONSECUTIVE
// sorted positions (compact region). Per wave: 16 group bboxes
// (one-time DPP reduce) + gbv[16] = exact max dmin per group (LDS,
// DPP-updated on dirty groups). Per iter: lane l tests group l&15 ->
// ballot -> uniform 16-bit mask -> s_cbranch per group. Dirty groups:
// byte-identical rn distance update; key re-chained over stored dmin
// regs only. Clean waves: lane63 re-submits cachedWaveKey. Skip is
// conservative (0.999 margin vs exact group max, r8-proven) ->
// bit-exact; all state deterministic in the input (replay-safe).
// ------------------------------------------------------------------
#define FPS_T 256
#define SLOTS 32

template <int CTRL>
__device__ __forceinline__ u64 dpp_max_step(u64 k) {
  int lo = (int)(unsigned)k;
  int hi = (int)(unsigned)(k >> 32);
  int slo = __builtin_amdgcn_update_dpp(0, lo, CTRL, 0xF, 0xF, true);
  int shi = __builtin_amdgcn_update_dpp(0, hi, CTRL, 0xF, 0xF, true);
  u64 s = ((u64)(unsigned)shi << 32) | (u64)(unsigned)slo;
  return s > k ? s : k;
}
__device__ __forceinline__ u64 dpp_max_all(u64 k) {
  k = dpp_max_step<0x111>(k); k = dpp_max_step<0x112>(k);
  k = dpp_max_step<0x114>(k); k = dpp_max_step<0x118>(k);
  k = dpp_max_step<0x142>(k); k = dpp_max_step<0x143>(k);
  return k;   // lane63 holds wave max
}
// nonneg float max across wave -> lane63 (bound_ctrl: invalid->0 = identity)
template <int CTRL>
__device__ __forceinline__ float dpp_fmax_step(float x) {
  int s = __builtin_amdgcn_update_dpp(0, __float_as_int(x), CTRL, 0xF, 0xF, true);
  return fmaxf(__int_as_float(s), x);
}
__device__ __forceinline__ float dpp_fmax_all(float x) {
  x = dpp_fmax_step<0x111>(x); x = dpp_fmax_step<0x112>(x);
  x = dpp_fmax_step<0x114>(x); x = dpp_fmax_step<0x118>(x);
  x = dpp_fmax_step<0x142>(x); x = dpp_fmax_step<0x143>(x);
  return x;
}
// nonneg float min across wave -> lane63 (old=+INF, bound_ctrl=false)
template <int CTRL>
__device__ __forceinline__ float dpp_fmin_step(float x) {
  int s = __builtin_amdgcn_update_dpp(0x7F800000, __float_as_int(x), CTRL, 0xF, 0xF, false);
  return fminf(__int_as_float(s), x);
}
__device__ __forceinline__ float dpp_fmin_all(float x) {
  x = dpp_fmin_step<0x111>(x); x = dpp_fmin_step<0x112>(x);
  x = dpp_fmin_step<0x114>(x); x = dpp_fmin_step<0x118>(x);
  x = dpp_fmin_step<0x142>(x); x = dpp_fmin_step<0x143>(x);
  return x;
}

__global__ __launch_bounds__(256, 1) void fps_kernel(
    const float* __restrict__ p, float* __restrict__ out, int* __restrict__ idx_i) {
#pragma clang fp contract(off)
  __shared__ float4 sp4[NP];                 // 128 KB
  __shared__ int win[MQ];                    // 8 KB (doubles as sort scratch)
  __shared__ u64 cnd[3];
  __shared__ float gbox[4][16][8];           // wave, group, {mnx,mny,mnz,_,mxx,mxy,mxz,_}
  __shared__ float gbv[4][16];               // exact max dmin per group
  int b = blockIdx.x;
  const float* pb = p + (size_t)b * NP * 3;
  float* out_newp = out;                               // [B][M][3]
  float* out_idxf = out + BB*MQ*3 + (size_t)BB*128*MQ; // [B][M] as float
  int t = threadIdx.x;
  int lane = t & 63;
  int wv = t >> 6;

  // ---- Phase A: load 32 points, histogram by 8-bit interleaved cell ----
  float tx[SLOTS], ty[SLOTS], tz[SLOTS];
  int cells[SLOTS];
  win[t] = 0;
  __syncthreads();
  #pragma unroll
  for (int s = 0; s < SLOTS; ++s) {
    int i = s * FPS_T + t;
    float x = pb[i*3+0], y = pb[i*3+1], z = pb[i*3+2];
    tx[s] = x; ty[s] = y; tz[s] = z;
    int cx = (int)(x * 8.0f); cx = cx < 0 ? 0 : (cx > 7 ? 7 : cx);
    int cy = (int)(y * 8.0f); cy = cy < 0 ? 0 : (cy > 7 ? 7 : cy);
    int cz = (int)(z * 4.0f); cz = cz < 0 ? 0 : (cz > 3 ? 3 : cz);
    int cell = (cx & 1) | ((cy & 1) << 1) | ((cz & 1) << 2)
             | (((cx >> 1) & 1) << 3) | (((cy >> 1) & 1) << 4) | ((cz >> 1) << 5)
             | ((cx >> 2) << 6) | ((cy >> 2) << 7);          // [0,256)
    cells[s] = cell;
    atomicAdd(&win[cell], 1);                // SUM: order-independent
  }
  __syncthreads();
  // ---- Phase B: exclusive prefix over 256 cells (deterministic) ----
  {
    int myCnt = win[t];
    __syncthreads();
    int* src = win; int* dst = win + 256;
    for (int off = 1; off < 256; off <<= 1) {
      int v = src[t];
      if (t >= off) v += src[t - off];
      dst[t] = v;
      int* tmp = src; src = dst; dst = tmp;
      __syncthreads();
    }
    int incl = src[t];
    __syncthreads();
    win[t] = incl - myCnt;                   // exclusive base
  }
  __syncthreads();
  // ---- Phase C: DETERMINISTIC scatter, wave-serialized (r8-proven) ----
  for (int w = 0; w < 4; ++w) {
    if (wv == w) {
      #pragma unroll
      for (int s = 0; s < SLOTS; ++s) {
        int c = cells[s];
        u64 eq = ~0ull;
        #pragma unroll
        for (int bit = 0; bit < 8; ++bit) {
          u64 bset = __ballot(((c >> bit) & 1) != 0);
          eq &= (((c >> bit) & 1) ? bset : ~bset);
        }
        int rank = (int)__popcll(eq & ((1ull << lane) - 1ull));
        int leader = (int)__builtin_ctzll(eq);
        int base = 0;
        if (lane == leader) base = atomicAdd(&win[c], (int)__popcll(eq));
        base = __shfl(base, leader);
        sp4[base + rank] = make_float4(tx[s], ty[s], tz[s],
                                       __int_as_float(s * FPS_T + t));
      }
    }
    __syncthreads();
  }
  // ---- Phase D: read my slots: slot s -> sorted pos wv*2048 + s*64 + lane ----
  unsigned notI[SLOTS];
  #pragma unroll
  for (int s = 0; s < SLOTS; ++s) {
    int q = wv * 2048 + s * 64 + lane;
    float4 v = sp4[q];
    tx[s] = v.x; ty[s] = v.y; tz[s] = v.z;
    notI[s] = ~(unsigned)__float_as_int(v.w);
  }
  __syncthreads();
  // ---- Phase E: rewrite sp4 ORIG-indexed ----
  #pragma unroll
  for (int s = 0; s < SLOTS; ++s) {
    int oi = (int)(~notI[s]);
    sp4[oi] = make_float4(tx[s], ty[s], tz[s], 0.0f);
  }
  // pack v2f groups; one-time group bbox via DPP reduce
  v2f px2[16], py2[16], pz2[16], dmin2[16];
  #pragma unroll
  for (int k = 0; k < 16; ++k) {
    px2[k] = (v2f){tx[2*k], tx[2*k+1]};
    py2[k] = (v2f){ty[2*k], ty[2*k+1]};
    pz2[k] = (v2f){tz[2*k], tz[2*k+1]};
    dmin2[k] = (v2f){INFINITY, INFINITY};
    float mnx = dpp_fmin_all(fminf(tx[2*k], tx[2*k+1]));
    float mny = dpp_fmin_all(fminf(ty[2*k], ty[2*k+1]));
    float mnz = dpp_fmin_all(fminf(tz[2*k], tz[2*k+1]));
    float mxx = dpp_fmax_all(fmaxf(tx[2*k], tx[2*k+1]));
    float mxy = dpp_fmax_all(fmaxf(ty[2*k], ty[2*k+1]));
    float mxz = dpp_fmax_all(fmaxf(tz[2*k], tz[2*k+1]));
    if (lane == 63) {
      gbox[wv][k][0] = mnx; gbox[wv][k][1] = mny; gbox[wv][k][2] = mnz;
      gbox[wv][k][4] = mxx; gbox[wv][k][5] = mxy; gbox[wv][k][6] = mxz;
      gbv[wv][k] = INFINITY;
    }
  }
  if (t < 3) cnd[t] = 0ull;
  if (t == 0) win[0] = 0;
  __syncthreads();
  // each lane caches the bbox of its test group g = lane & 15
  int g = lane & 15;
  float gmnx = gbox[wv][g][0], gmny = gbox[wv][g][1], gmnz = gbox[wv][g][2];
  float gmxx = gbox[wv][g][4], gmxy = gbox[wv][g][5], gmxz = gbox[wv][g][6];
  float lx = sp4[0].x, ly = sp4[0].y, lz = sp4[0].z;

  u64 cachedWaveKey = 0ull;   // lane63's copy is the wave key
  for (int j = 1; j < MQ; ++j) {
    // uniform group-dirty mask: lane tests group lane&15
    float cbv = gbv[wv][g];
    float dxm = fmaxf(fmaxf(gmnx - lx, lx - gmxx), 0.0f);
    float dym = fmaxf(fmaxf(gmny - ly, ly - gmxy), 0.0f);
    float dzm = fmaxf(fmaxf(gmnz - lz, lz - gmxz), 0.0f);
    float lbsq = dxm*dxm + dym*dym + dzm*dzm;
    bool gd = (lbsq * 0.999f < cbv);         // conservative (r8-proven margin)
    u64 bm = __ballot(gd);
    unsigned m16 = (unsigned)(bm & 0xFFFFull);   // lanes 0-15's verdicts (uniform)
    if (m16) {
      v2f l2x = (v2f){lx, lx}, l2y = (v2f){ly, ly}, l2z = (v2f){lz, lz};
      #pragma unroll
      for (int k = 0; k < 16; ++k) {
        if (m16 & (1u << k)) {               // uniform branch per group
          v2f dx = px2[k] - l2x;
          v2f dy = py2[k] - l2y;
          v2f dz = pz2[k] - l2z;
          v2f dd = ((dx*dx) + (dy*dy)) + (dz*dz);
          v2f dm = __builtin_elementwise_min(dmin2[k], dd);
          dmin2[k] = dm;
          float nb = dpp_fmax_all(fmaxf(dm.x, dm.y));  // exact group max dmin
          if (lane == 63) gbv[wv][k] = nb;
        }
      }
      // re-chain lane key over stored dmin (no distance math for clean groups)
      u64 c0 = 0ull, c1 = 0ull;
      #pragma unroll
      for (int k = 0; k < 16; ++k) {
        u64 k0 = ((u64)__float_as_uint(dmin2[k].x) << 32) | (u64)notI[2*k];
        u64 k1 = ((u64)__float_as_uint(dmin2[k].y) << 32) | (u64)notI[2*k+1];
        c0 = k0 > c0 ? k0 : c0;
        c1 = k1 > c1 ? k1 : c1;
      }
      u64 key = c0 > c1 ? c0 : c1;
      cachedWaveKey = dpp_max_all(key);      // lane63 = wave max
    }
    int slot = j % 3;
    if (lane == 63) atomicMax(&cnd[slot], cachedWaveKey);
    __syncthreads();                         // single barrier (r6-proven tail)
    u64 kw = cnd[slot];
    if (t == 0) cnd[(j + 2) % 3] = 0ull;
    int wi = (int)(~(unsigned)kw);           // ORIGINAL index
    float4 c = sp4[wi];                      // one b128 broadcast
    lx = c.x; ly = c.y; lz = c.z;
    if (t == 0) win[j] = wi;
  }

  __syncthreads();
  // bulk coalesced epilogue
  #pragma unroll
  for (int k2 = 0; k2 < MQ / FPS_T; ++k2) {
    int j = k2 * FPS_T + t;
    int wi = win[j];
    out_idxf[b*MQ + j] = (float)wi;
    idx_i[b*MQ + j] = wi;
    float4 c = sp4[wi];
    float* np_ = &out_newp[(size_t)(b*MQ + j) * 3];
    np_[0] = c.x; np_[1] = c.y; np_[2] = c.z;
  }
}

// ------------------------------------------------------------------
// ball query: one wave per query (r1-proven, unchanged)
// ------------------------------------------------------------------
__global__ __launch_bounds__(256) void ballq_kernel(
    const float* __restrict__ p, const float* __restrict__ newp,
    int* __restrict__ nidx) {
  int qid = blockIdx.x * 4 + (threadIdx.x >> 6);
  int lane = threadIdx.x & 63;
  int b = qid >> 11;
  const float* pb = p + (size_t)b * NP * 3;
  float qx = newp[qid*3], qy = newp[qid*3+1], qz = newp[qid*3+2];
  float sq_q = __fadd_rn(__fadd_rn(__fmul_rn(qx,qx), __fmul_rn(qy,qy)), __fmul_rn(qz,qz));
  const float R2 = (float)(0.1 * 0.1);
  int found = 0, first = -1;
  int* outp = nidx + (size_t)qid * KS;
  for (int base = 0; base < NP; base += 64) {
    int n = base + lane;
    float x = pb[n*3], y = pb[n*3+1], z = pb[n*3+2];
    float sq_p = __fadd_rn(__fadd_rn(__fmul_rn(x,x), __fmul_rn(y,y)), __fmul_rn(z,z));
    float dot  = __fadd_rn(__fadd_rn(__fmul_rn(qx,x), __fmul_rn(qy,y)), __fmul_rn(qz,z));
    float d2   = __fadd_rn(__fadd_rn(sq_q, sq_p), __fmul_rn(-2.0f, dot));
    bool hit = d2 < R2;
    unsigned long long mask = __ballot(hit);
    if (mask) {
      if (first < 0) first = base + __builtin_ctzll(mask);
      int cnt = __popcll(mask);
      if (found < KS) {
        int rank = __popcll(mask & ((1ull << lane) - 1ull));
        if (hit && found + rank < KS) outp[found + rank] = n;
      }
      found += cnt;
      if (found >= KS) break;
    }
  }
  int fcl = found < KS ? found : KS;
  int padv = first < 0 ? 0 : first;
  if (lane >= fcl && lane < KS) outp[lane] = padv;
}

// ------------------------------------------------------------------
// P1: conv1 over gathered x, accumulate per-channel sum/sumsq.
// ------------------------------------------------------------------
__global__ __launch_bounds__(256) void p1_kernel(
    const float* __restrict__ p, const float* __restrict__ newp,
    const float* __restrict__ ft, const int* __restrict__ nidx,
    const float* __restrict__ w1p, float* __restrict__ stats1) {
  __shared__ __align__(16) float xbuf[4][KS][68];
  __shared__ float wbs[4][64], wbq[4][64];
  int wv = threadIdx.x >> 6, lane = threadIdx.x & 63;
  int qid = blockIdx.x * 4 + wv;
  int b = qid >> 11;
  int nv = (lane < KS) ? nidx[(size_t)qid * KS + lane] : 0;
  float qx = newp[qid*3], qy = newp[qid*3+1], qz = newp[qid*3+2];
  for (int kk = 0; kk < KS; ++kk) {
    int n = __shfl(nv, kk);
    const float* fr = ft + ((size_t)b * NP + n) * 64;
    xbuf[wv][kk][3 + lane] = fr[lane];
    if (lane < 3) {
      const float* pp = p + ((size_t)b * NP + n) * 3;
      float qc = (lane == 0) ? qx : ((lane == 1) ? qy : qz);
      xbuf[wv][kk][lane] = __fsub_rn(pp[lane], qc);
    }
    if (lane == 3) xbuf[wv][kk][67] = 0.0f;
  }
  __syncthreads();
  const float4* wr = (const float4*)(w1p + lane * 68);
  float4 wreg[17];
  #pragma unroll
  for (int c4 = 0; c4 < 17; ++c4) wreg[c4] = wr[c4];
  float ss = 0.f, qq = 0.f;
  for (int kk = 0; kk < KS; ++kk) {
    const float4* xr = (const float4*)(&xbuf[wv][kk][0]);
    float acc = 0.f;
    #pragma unroll
    for (int c4 = 0; c4 < 17; ++c4) {
      float4 w = wreg[c4]; float4 x = xr[c4];
      acc += w.x*x.x + w.y*x.y + w.z*x.z + w.w*x.w;
    }
    ss += acc; qq += acc * acc;
  }
  wbs[wv][lane] = ss; wbq[wv][lane] = qq;
  __syncthreads();
  if (threadIdx.x < 64) {
    float s  = wbs[0][threadIdx.x] + wbs[1][threadIdx.x] + wbs[2][threadIdx.x] + wbs[3][threadIdx.x];
    float s2 = wbq[0][threadIdx.x] + wbq[1][threadIdx.x] + wbq[2][threadIdx.x] + wbq[3][threadIdx.x];
    int slice = blockIdx.x & 63;
    atomicAdd(&stats1[(slice*2+0)*64 + threadIdx.x], s);
    atomicAdd(&stats1[(slice*2+1)*64 + threadIdx.x], s2);
  }
}

// ------------------------------------------------------------------
__global__ void fin1_kernel(const float* __restrict__ stats1,
                            const float* __restrict__ g, const float* __restrict__ bb,
                            float* __restrict__ sc) {
  int o = threadIdx.x;
  float s = 0.f, q = 0.f;
  for (int sl = 0; sl < 64; ++sl) { s += stats1[(sl*2+0)*64+o]; q += stats1[(sl*2+1)*64+o]; }
  const float cnt = (float)(BB * MQ * KS);
  float mean = s / cnt;
  float var = q / cnt - mean * mean;
  float rstd = 1.0f / sqrtf(var + 1e-5f);
  float gs = g[o] * rstd;
  sc[o] = gs;
  sc[64+o] = bb[o] - mean * gs;
}

__global__ void fin2_kernel(const float* __restrict__ stats2,
                            const float* __restrict__ g, const float* __restrict__ bb,
                            float* __restrict__ sc) {
  int o = threadIdx.x;
  float s = 0.f, q = 0.f;
  for (int sl = 0; sl < 64; ++sl) { s += stats2[(sl*2+0)*128+o]; q += stats2[(sl*2+1)*128+o]; }
  const float cnt = (float)(BB * MQ * KS);
  float mean = s / cnt;
  float var = q / cnt - mean * mean;
  float rstd = 1.0f / sqrtf(var + 1e-5f);
  float gs = g[o] * rstd;
  sc[o] = gs;
  sc[128+o] = bb[o] - mean * gs;
}

// ------------------------------------------------------------------
// P2: conv1 recompute, bn1+relu, conv2, stats2 + per-query max over K
// ------------------------------------------------------------------
__global__ __launch_bounds__(256) void p2_kernel(
    const float* __restrict__ p, const float* __restrict__ newp,
    const float* __restrict__ ft, const int* __restrict__ nidx,
    const float* __restrict__ w1p, const float* __restrict__ w2,
    const float* __restrict__ sc1,
    float* __restrict__ stats2, float* __restrict__ maxy2) {
  __shared__ __align__(16) float xbuf[4][KS][68];
  __shared__ float wbs[4][128], wbq[4][128];
  int wv = threadIdx.x >> 6, lane = threadIdx.x & 63;
  int qid = blockIdx.x * 4 + wv;
  int b = qid >> 11;
  int nv = (lane < KS) ? nidx[(size_t)qid * KS + lane] : 0;
  float qx = newp[qid*3], qy = newp[qid*3+1], qz = newp[qid*3+2];
  for (int kk = 0; kk < KS; ++kk) {
    int n = __shfl(nv, kk);
    const float* fr = ft + ((size_t)b * NP + n) * 64;
    xbuf[wv][kk][3 + lane] = fr[lane];
    if (lane < 3) {
      const float* pp = p + ((size_t)b * NP + n) * 3;
      float qc = (lane == 0) ? qx : ((lane == 1) ? qy : qz);
      xbuf[wv][kk][lane] = __fsub_rn(pp[lane], qc);
    }
    if (lane == 3) xbuf[wv][kk][67] = 0.0f;
  }
  __syncthreads();
  {
    const float4* wr = (const float4*)(w1p + lane * 68);
    float4 wreg[17];
    #pragma unroll
    for (int c4 = 0; c4 < 17; ++c4) wreg[c4] = wr[c4];
    float s1v = sc1[lane], t1v = sc1[64 + lane];
    for (int kk = 0; kk < KS; ++kk) {
      const float4* xr = (const float4*)(&xbuf[wv][kk][0]);
      float acc = 0.f;
      #pragma unroll
      for (int c4 = 0; c4 < 17; ++c4) {
        float4 w = wreg[c4]; float4 x = xr[c4];
        acc += w.x*x.x + w.y*x.y + w.z*x.z + w.w*x.w;
      }
      float h = fmaxf(0.0f, fmaf(acc, s1v, t1v));
      xbuf[wv][kk][lane] = h;
    }
  }
  const float4* w2a = (const float4*)(w2 + (size_t)lane * 64);
  const float4* w2b = (const float4*)(w2 + (size_t)(lane + 64) * 64);
  float4 wra[16], wrb[16];
  #pragma unroll
  for (int c4 = 0; c4 < 16; ++c4) { wra[c4] = w2a[c4]; wrb[c4] = w2b[c4]; }
  float ss0 = 0.f, qq0 = 0.f, mx0 = -INFINITY;
  float ss1 = 0.f, qq1 = 0.f, mx1 = -INFINITY;
  for (int kk = 0; kk < KS; ++kk) {
    const float4* hr = (const float4*)(&xbuf[wv][kk][0]);
    float a0 = 0.f, a1 = 0.f;
    #pragma unroll
    for (int c4 = 0; c4 < 16; ++c4) {
      float4 h4 = hr[c4];
      float4 wa = wra[c4]; float4 wb = wrb[c4];
      a0 += wa.x*h4.x + wa.y*h4.y + wa.z*h4.z + wa.w*h4.w;
      a1 += wb.x*h4.x + wb.y*h4.y + wb.z*h4.z + wb.w*h4.w;
    }
    ss0 += a0; qq0 += a0*a0; mx0 = fmaxf(mx0, a0);
    ss1 += a1; qq1 += a1*a1; mx1 = fmaxf(mx1, a1);
  }
  maxy2[(size_t)qid * 128 + lane] = mx0;
  maxy2[(size_t)qid * 128 + 64 + lane] = mx1;
  wbs[wv][lane] = ss0; wbs[wv][64+lane] = ss1;
  wbq[wv][lane] = qq0; wbq[wv][64+lane] = qq1;
  __syncthreads();
  if (threadIdx.x < 128) {
    float s  = wbs[0][threadIdx.x] + wbs[1][threadIdx.x] + wbs[2][threadIdx.x] + wbs[3][threadIdx.x];
    float s2 = wbq[0][threadIdx.x] + wbq[1][threadIdx.x] + wbq[2][threadIdx.x] + wbq[3][threadIdx.x];
    int slice = blockIdx.x & 63;
    atomicAdd(&stats2[(slice*2+0)*128 + threadIdx.x], s);
    atomicAdd(&stats2[(slice*2+1)*128 + threadIdx.x], s2);
  }
}

// ------------------------------------------------------------------
__global__ __launch_bounds__(256) void p3_kernel(
    const float* __restrict__ ft, const int* __restrict__ idx_i,
    const float* __restrict__ w_skip, const float* __restrict__ b_skip,
    const float* __restrict__ sc2, const float* __restrict__ maxy2,
    float* __restrict__ outf) {
  int wv = threadIdx.x >> 6, lane = threadIdx.x & 63;
  int qid = blockIdx.x * 4 + wv;
  int b = qid >> 11, m = qid & (MQ - 1);
  int n = idx_i[qid];
  const float4* f4 = (const float4*)(ft + ((size_t)b * NP + n) * 64);
  const float4* wa = (const float4*)(w_skip + (size_t)lane * 64);
  const float4* wb = (const float4*)(w_skip + (size_t)(lane + 64) * 64);
  float a0 = b_skip[lane], a1 = b_skip[lane + 64];
  #pragma unroll
  for (int c4 = 0; c4 < 16; ++c4) {
    float4 x = f4[c4]; float4 u = wa[c4]; float4 v = wb[c4];
    a0 += u.x*x.x + u.y*x.y + u.z*x.z + u.w*x.w;
    a1 += v.x*x.x + v.y*x.y + v.z*x.z + v.w*x.w;
  }
  float v0 = maxy2[(size_t)qid * 128 + lane];
  float v1 = maxy2[(size_t)qid * 128 + 64 + lane];
  float r0 = fmaxf(0.0f, fmaf(v0, sc2[lane],      sc2[128 + lane])      + a0);
  float r1 = fmaxf(0.0f, fmaf(v1, sc2[lane + 64], sc2[128 + lane + 64]) + a1);
  outf[((size_t)b * 128 + lane) * MQ + m] = r0;
  outf[((size_t)b * 128 + lane + 64) * MQ + m] = r1;
}

// ------------------------------------------------------------------
extern "C" void kernel_launch(void* const* d_in, const int* in_sizes, int n_in,
                              void* d_out, int out_size, void* d_ws, size_t ws_size,
                              hipStream_t stream) {
  (void)in_sizes; (void)n_in; (void)out_size; (void)ws_size;
  const float* p   = (const float*)d_in[0];
  const float* f   = (const float*)d_in[1];
  const float* w1  = (const float*)d_in[2];
  const float* g1  = (const float*)d_in[3];
  const float* b1  = (const float*)d_in[4];
  const float* w2  = (const float*)d_in[5];
  const float* g2  = (const float*)d_in[6];
  const float* b2  = (const float*)d_in[7];
  const float* wsk = (const float*)d_in[8];
  const float* bsk = (const float*)d_in[9];
  float* out = (float*)d_out;
  float* wsf = (float*)d_ws;

  float* ft    = wsf + WS_FT;
  int*   nidx  = (int*)(wsf + WS_NIDX);
  int*   idxi  = (int*)(wsf + WS_IDXI);
  float* st1   = wsf + WS_ST1;
  float* st2   = wsf + WS_ST2;
  float* sc1   = wsf + WS_SC1;
  float* sc2   = wsf + WS_SC2;
  float* maxy2 = wsf + WS_MAXY2;
  float* w1p   = wsf + WS_W1P;

  float* out_newp = out;
  float* out_f    = out + BB*MQ*3;

  (void)hipMemsetAsync(st1, 0, (8192 + 16384) * sizeof(float), stream);

  transpose_f_kernel<<<dim3(NP/64, BB), 256, 0, stream>>>(f, ft);
  prep_w1_kernel<<<17, 256, 0, stream>>>(w1, w1p);
  fps_kernel<<<BB, FPS_T, 0, stream>>>(p, out, idxi);
  ballq_kernel<<<BB*MQ/4, 256, 0, stream>>>(p, out_newp, nidx);
  p1_kernel<<<BB*MQ/4, 256, 0, stream>>>(p, out_newp, ft, nidx, w1p, st1);
  fin1_kernel<<<1, 64, 0, stream>>>(st1, g1, b1, sc1);
  p2_kernel<<<BB*MQ/4, 256, 0, stream>>>(p, out_newp, ft, nidx, w1p, w2, sc1, st2, maxy2);
  fin2_kernel<<<1, 128, 0, stream>>>(st2, g2, b2, sc2);
  p3_kernel<<<BB*MQ/4, 256, 0, stream>>>(ft, idxi, wsk, bsk, sc2, maxy2, out_f);
}

// Round 11
// 3187.390 us; speedup vs baseline: 1.0448x; 1.0448x over previous
//
#include <hip/hip_runtime.h>
#include <math.h>

#define BB 4
#define NP 8192
#define CF 64
#define MQ 2048
#define KS 32

// ---- workspace layout (float indices) ----
#define WS_FT     0u
#define WS_NIDX   2097152u
#define WS_IDXI   2359296u
#define WS_ST1    2367488u
#define WS_ST2    2375680u
#define WS_SC1    2392064u
#define WS_SC2    2392192u
#define WS_MAXY2  2392448u
#define WS_W1P    3441024u

typedef float v2f __attribute__((ext_vector_type(2)));
typedef unsigned long long u64;

// ------------------------------------------------------------------
// transpose f [B][64][N] -> ft [B][N][64]
// ------------------------------------------------------------------
__global__ __launch_bounds__(256) void transpose_f_kernel(
    const float* __restrict__ f, float* __restrict__ ft) {
  __shared__ float tile[64][65];
  int b = blockIdx.y;
  int n0 = blockIdx.x * 64;
  int cc = threadIdx.x >> 6;
  int nn = threadIdx.x & 63;
  #pragma unroll
  for (int r = 0; r < 16; ++r) {
    int c = cc * 16 + r;
    tile[c][nn] = f[((size_t)b * 64 + c) * NP + n0 + nn];
  }
  __syncthreads();
  #pragma unroll
  for (int r = 0; r < 16; ++r) {
    int nl = cc * 16 + r;
    ft[((size_t)b * NP + n0 + nl) * 64 + nn] = tile[nn][nl];
  }
}

// ------------------------------------------------------------------
__global__ void prep_w1_kernel(const float* __restrict__ w1, float* __restrict__ w1p) {
  int i = blockIdx.x * 256 + threadIdx.x;
  if (i < 64 * 68) {
    int o = i / 68, c = i % 68;
    w1p[i] = (c < 67) ? w1[o * 67 + c] : 0.0f;
  }
}

// ------------------------------------------------------------------
// FPS v10: r10's group-granular prune, spill-free.
// r10 lesson (counters): VGPR=256 + FETCH 216->902KB = scratch spills
// drowned the prune. v10 register discipline: histogram keeps only
// cells[32]; scatter RELOADS coords from global (L2-hot,
// deterministic); scan arrays built directly from sorted LDS (no
// duplicate tx/ty/tz); indices packed 2x16-bit. Live ~205 regs.
// Leaner loop: gbv refreshed via one ds_read issued right after the
// barrier (exact for next iter; concurrent skip-vs-rescan is
// idempotent -> deterministic); lazy per-group keys gkey[16] rebuilt
// only for dirty groups + 16-way tree max (vs 160-inst full rechain).
// Tail = r6-proven: triple-buffered cnd atomicMax + ONE barrier/iter.
// Invariants: byte-identical rn scan math; 0.999 conservative skip
// (skip => state provably unchanged; winner's group always dirty:
// lb=0 < gbv); key (f32bits(dmin)<<32)|~idx, first-occurrence ties;
// deterministic ballot-leader counting sort (r8-proven).
// ------------------------------------------------------------------
#define FPS_T 256
#define SLOTS 32

template <int CTRL>
__device__ __forceinline__ u64 dpp_max_step(u64 k) {
  int lo = (int)(unsigned)k;
  int hi = (int)(unsigned)(k >> 32);
  int slo = __builtin_amdgcn_update_dpp(0, lo, CTRL, 0xF, 0xF, true);
  int shi = __builtin_amdgcn_update_dpp(0, hi, CTRL, 0xF, 0xF, true);
  u64 s = ((u64)(unsigned)shi << 32) | (u64)(unsigned)slo;
  return s > k ? s : k;
}
__device__ __forceinline__ u64 dpp_max_all(u64 k) {
  k = dpp_max_step<0x111>(k); k = dpp_max_step<0x112>(k);
  k = dpp_max_step<0x114>(k); k = dpp_max_step<0x118>(k);
  k = dpp_max_step<0x142>(k); k = dpp_max_step<0x143>(k);
  return k;   // lane63 holds wave max
}
template <int CTRL>
__device__ __forceinline__ float dpp_fmax_step(float x) {
  int s = __builtin_amdgcn_update_dpp(0, __float_as_int(x), CTRL, 0xF, 0xF, true);
  return fmaxf(__int_as_float(s), x);
}
__device__ __forceinline__ float dpp_fmax_all(float x) {   // nonneg only
  x = dpp_fmax_step<0x111>(x); x = dpp_fmax_step<0x112>(x);
  x = dpp_fmax_step<0x114>(x); x = dpp_fmax_step<0x118>(x);
  x = dpp_fmax_step<0x142>(x); x = dpp_fmax_step<0x143>(x);
  return x;
}
template <int CTRL>
__device__ __forceinline__ float dpp_fmin_step(float x) {
  int s = __builtin_amdgcn_update_dpp(0x7F800000, __float_as_int(x), CTRL, 0xF, 0xF, false);
  return fminf(__int_as_float(s), x);
}
__device__ __forceinline__ float dpp_fmin_all(float x) {
  x = dpp_fmin_step<0x111>(x); x = dpp_fmin_step<0x112>(x);
  x = dpp_fmin_step<0x114>(x); x = dpp_fmin_step<0x118>(x);
  x = dpp_fmin_step<0x142>(x); x = dpp_fmin_step<0x143>(x);
  return x;
}

__device__ __forceinline__ int cell_of(float x, float y, float z) {
  int cx = (int)(x * 8.0f); cx = cx < 0 ? 0 : (cx > 7 ? 7 : cx);
  int cy = (int)(y * 8.0f); cy = cy < 0 ? 0 : (cy > 7 ? 7 : cy);
  int cz = (int)(z * 4.0f); cz = cz < 0 ? 0 : (cz > 3 ? 3 : cz);
  return (cx & 1) | ((cy & 1) << 1) | ((cz & 1) << 2)
       | (((cx >> 1) & 1) << 3) | (((cy >> 1) & 1) << 4) | ((cz >> 1) << 5)
       | ((cx >> 2) << 6) | ((cy >> 2) << 7);          // [0,256)
}

__global__ __launch_bounds__(256, 1) void fps_kernel(
    const float* __restrict__ p, float* __restrict__ out, int* __restrict__ idx_i) {
#pragma clang fp contract(off)
  __shared__ float4 sp4[NP];                 // 128 KB
  __shared__ int win[MQ];                    // 8 KB (doubles as sort scratch)
  __shared__ u64 cnd[3];
  __shared__ float gbox[4][16][8];           // wave, group, {mnx,mny,mnz,_,mxx,mxy,mxz,_}
  __shared__ float gbv[4][16];               // exact max dmin per group
  int b = blockIdx.x;
  const float* pb = p + (size_t)b * NP * 3;
  float* out_newp = out;                               // [B][M][3]
  float* out_idxf = out + BB*MQ*3 + (size_t)BB*128*MQ; // [B][M] as float
  int t = threadIdx.x;
  int lane = t & 63;
  int wv = t >> 6;

  // ---- Phase A: histogram by 8-bit interleaved cell (coords not kept) ----
  int cells[SLOTS];
  win[t] = 0;
  __syncthreads();
  #pragma unroll
  for (int s = 0; s < SLOTS; ++s) {
    int i = s * FPS_T + t;
    int c = cell_of(pb[i*3+0], pb[i*3+1], pb[i*3+2]);
    cells[s] = c;
    atomicAdd(&win[c], 1);                   // SUM: order-independent
  }
  __syncthreads();
  // ---- Phase B: exclusive prefix over 256 cells (deterministic) ----
  {
    int myCnt = win[t];
    __syncthreads();
    int* src = win; int* dst = win + 256;
    for (int off = 1; off < 256; off <<= 1) {
      int v = src[t];
      if (t >= off) v += src[t - off];
      dst[t] = v;
      int* tmp = src; src = dst; dst = tmp;
      __syncthreads();
    }
    int incl = src[t];
    __syncthreads();
    win[t] = incl - myCnt;                   // exclusive base
  }
  __syncthreads();
  // ---- Phase C: DETERMINISTIC scatter (reload coords; r8-proven) ----
  for (int w = 0; w < 4; ++w) {
    if (wv == w) {
      #pragma unroll
      for (int s = 0; s < SLOTS; ++s) {
        int i = s * FPS_T + t;
        float x = pb[i*3+0], y = pb[i*3+1], z = pb[i*3+2];   // L2-hot reload
        int c = cells[s];
        u64 eq = ~0ull;
        #pragma unroll
        for (int bit = 0; bit < 8; ++bit) {
          u64 bset = __ballot(((c >> bit) & 1) != 0);
          eq &= (((c >> bit) & 1) ? bset : ~bset);
        }
        int rank = (int)__popcll(eq & ((1ull << lane) - 1ull));
        int leader = (int)__builtin_ctzll(eq);
        int base = 0;
        if (lane == leader) base = atomicAdd(&win[c], (int)__popcll(eq));
        base = __shfl(base, leader);
        sp4[base + rank] = make_float4(x, y, z, __int_as_float(i));
      }
    }
    __syncthreads();
  }
  // ---- Phase D: build scan state directly from sorted LDS ----
  v2f px2[16], py2[16], pz2[16], dmin2[16];
  unsigned pkidx[16];                        // idx0 | (idx1<<16)
  u64 gkey[16];
  #pragma unroll
  for (int k = 0; k < 16; ++k) {
    int q0 = wv * 2048 + (2*k) * 64 + lane;
    float4 v0 = sp4[q0];
    float4 v1 = sp4[q0 + 64];
    px2[k] = (v2f){v0.x, v1.x};
    py2[k] = (v2f){v0.y, v1.y};
    pz2[k] = (v2f){v0.z, v1.z};
    unsigned i0 = (unsigned)__float_as_int(v0.w);
    unsigned i1 = (unsigned)__float_as_int(v1.w);
    pkidx[k] = i0 | (i1 << 16);
    dmin2[k] = (v2f){INFINITY, INFINITY};
    gkey[k] = ((u64)0x7F800000u << 32) | (u64)(~i0);   // overwritten at j=1 (all dirty)
    float mnx = dpp_fmin_all(fminf(v0.x, v1.x));
    float mny = dpp_fmin_all(fminf(v0.y, v1.y));
    float mnz = dpp_fmin_all(fminf(v0.z, v1.z));
    float mxx = dpp_fmax_all(fmaxf(v0.x, v1.x));
    float mxy = dpp_fmax_all(fmaxf(v0.y, v1.y));
    float mxz = dpp_fmax_all(fmaxf(v0.z, v1.z));
    if (lane == 63) {
      gbox[wv][k][0] = mnx; gbox[wv][k][1] = mny; gbox[wv][k][2] = mnz;
      gbox[wv][k][4] = mxx; gbox[wv][k][5] = mxy; gbox[wv][k][6] = mxz;
      gbv[wv][k] = INFINITY;
    }
  }
  if (t < 3) cnd[t] = 0ull;
  if (t == 0) win[0] = 0;
  __syncthreads();
  // ---- Phase E: rewrite sp4 ORIG-indexed (coords from regs) ----
  #pragma unroll
  for (int k = 0; k < 16; ++k) {
    int i0 = (int)(pkidx[k] & 0xFFFFu);
    int i1 = (int)(pkidx[k] >> 16);
    sp4[i0] = make_float4(px2[k].x, py2[k].x, pz2[k].x, 0.0f);
    sp4[i1] = make_float4(px2[k].y, py2[k].y, pz2[k].y, 0.0f);
  }
  __syncthreads();
  // lane caches bbox of its test group g = lane & 15
  int g = lane & 15;
  float gmnx = gbox[wv][g][0], gmny = gbox[wv][g][1], gmnz = gbox[wv][g][2];
  float gmxx = gbox[wv][g][4], gmxy = gbox[wv][g][5], gmxz = gbox[wv][g][6];
  float gbvReg = INFINITY;
  float lx = sp4[0].x, ly = sp4[0].y, lz = sp4[0].z;

  u64 cachedWaveKey = 0ull;   // lane63's copy is the wave key
  for (int j = 1; j < MQ; ++j) {
    // uniform group-dirty mask (lane l's verdict for group l&15; low 16 used)
    float dxm = fmaxf(fmaxf(gmnx - lx, lx - gmxx), 0.0f);
    float dym = fmaxf(fmaxf(gmny - ly, ly - gmxy), 0.0f);
    float dzm = fmaxf(fmaxf(gmnz - lz, lz - gmxz), 0.0f);
    float lbsq = dxm*dxm + dym*dym + dzm*dzm;
    bool gd = (lbsq * 0.999f < gbvReg);      // conservative (r8-proven margin)
    u64 bm = __ballot(gd);
    unsigned m16 = (unsigned)(bm & 0xFFFFull);
    if (m16) {
      v2f l2x = (v2f){lx, lx}, l2y = (v2f){ly, ly}, l2z = (v2f){lz, lz};
      #pragma unroll
      for (int k = 0; k < 16; ++k) {
        if (m16 & (1u << k)) {               // uniform branch per group
          v2f dx = px2[k] - l2x;
          v2f dy = py2[k] - l2y;
          v2f dz = pz2[k] - l2z;
          v2f dd = ((dx*dx) + (dy*dy)) + (dz*dz);
          v2f dm = __builtin_elementwise_min(dmin2[k], dd);
          dmin2[k] = dm;
          unsigned pi = pkidx[k];
          u64 k0 = ((u64)__float_as_uint(dm.x) << 32) | (u64)(~(pi & 0xFFFFu));
          u64 k1 = ((u64)__float_as_uint(dm.y) << 32) | (u64)(~(pi >> 16));
          gkey[k] = k0 > k1 ? k0 : k1;
          float gm = dpp_fmax_all(fmaxf(dm.x, dm.y));   // exact group max dmin
          if (lane == 63) gbv[wv][k] = gm;
        }
      }
      // tree-max over 16 cached group keys
      u64 c0 = 0ull, c1 = 0ull;
      #pragma unroll
      for (int k = 0; k < 16; k += 2) {
        c0 = gkey[k]   > c0 ? gkey[k]   : c0;
        c1 = gkey[k+1] > c1 ? gkey[k+1] : c1;
      }
      u64 key = c0 > c1 ? c0 : c1;
      cachedWaveKey = dpp_max_all(key);      // lane63 = wave max
    }
    int slot = j % 3;
    if (lane == 63) atomicMax(&cnd[slot], cachedWaveKey);
    __syncthreads();                         // single barrier (r6-proven tail)
    u64 kw = cnd[slot];
    if (t == 0) cnd[(j + 2) % 3] = 0ull;
    gbvReg = gbv[wv][g];                     // post-barrier refresh (latency hidden)
    int wi = (int)(~(unsigned)kw);           // ORIGINAL index
    float4 c = sp4[wi];                      // one b128 broadcast
    lx = c.x; ly = c.y; lz = c.z;
    if (t == 0) win[j] = wi;
  }

  __syncthreads();
  // bulk coalesced epilogue
  #pragma unroll
  for (int k2 = 0; k2 < MQ / FPS_T; ++k2) {
    int j = k2 * FPS_T + t;
    int wi = win[j];
    out_idxf[b*MQ + j] = (float)wi;
    idx_i[b*MQ + j] = wi;
    float4 c = sp4[wi];
    float* np_ = &out_newp[(size_t)(b*MQ + j) * 3];
    np_[0] = c.x; np_[1] = c.y; np_[2] = c.z;
  }
}

// ------------------------------------------------------------------
// ball query: one wave per query (r1-proven, unchanged)
// ------------------------------------------------------------------
__global__ __launch_bounds__(256) void ballq_kernel(
    const float* __restrict__ p, const float* __restrict__ newp,
    int* __restrict__ nidx) {
  int qid = blockIdx.x * 4 + (threadIdx.x >> 6);
  int lane = threadIdx.x & 63;
  int b = qid >> 11;
  const float* pb = p + (size_t)b * NP * 3;
  float qx = newp[qid*3], qy = newp[qid*3+1], qz = newp[qid*3+2];
  float sq_q = __fadd_rn(__fadd_rn(__fmul_rn(qx,qx), __fmul_rn(qy,qy)), __fmul_rn(qz,qz));
  const float R2 = (float)(0.1 * 0.1);
  int found = 0, first = -1;
  int* outp = nidx + (size_t)qid * KS;
  for (int base = 0; base < NP; base += 64) {
    int n = base + lane;
    float x = pb[n*3], y = pb[n*3+1], z = pb[n*3+2];
    float sq_p = __fadd_rn(__fadd_rn(__fmul_rn(x,x), __fmul_rn(y,y)), __fmul_rn(z,z));
    float dot  = __fadd_rn(__fadd_rn(__fmul_rn(qx,x), __fmul_rn(qy,y)), __fmul_rn(qz,z));
    float d2   = __fadd_rn(__fadd_rn(sq_q, sq_p), __fmul_rn(-2.0f, dot));
    bool hit = d2 < R2;
    unsigned long long mask = __ballot(hit);
    if (mask) {
      if (first < 0) first = base + __builtin_ctzll(mask);
      int cnt = __popcll(mask);
      if (found < KS) {
        int rank = __popcll(mask & ((1ull << lane) - 1ull));
        if (hit && found + rank < KS) outp[found + rank] = n;
      }
      found += cnt;
      if (found >= KS) break;
    }
  }
  int fcl = found < KS ? found : KS;
  int padv = first < 0 ? 0 : first;
  if (lane >= fcl && lane < KS) outp[lane] = padv;
}

// ------------------------------------------------------------------
// P1: conv1 over gathered x, accumulate per-channel sum/sumsq.
// ------------------------------------------------------------------
__global__ __launch_bounds__(256) void p1_kernel(
    const float* __restrict__ p, const float* __restrict__ newp,
    const float* __restrict__ ft, const int* __restrict__ nidx,
    const float* __restrict__ w1p, float* __restrict__ stats1) {
  __shared__ __align__(16) float xbuf[4][KS][68];
  __shared__ float wbs[4][64], wbq[4][64];
  int wv = threadIdx.x >> 6, lane = threadIdx.x & 63;
  int qid = blockIdx.x * 4 + wv;
  int b = qid >> 11;
  int nv = (lane < KS) ? nidx[(size_t)qid * KS + lane] : 0;
  float qx = newp[qid*3], qy = newp[qid*3+1], qz = newp[qid*3+2];
  for (int kk = 0; kk < KS; ++kk) {
    int n = __shfl(nv, kk);
    const float* fr = ft + ((size_t)b * NP + n) * 64;
    xbuf[wv][kk][3 + lane] = fr[lane];
    if (lane < 3) {
      const float* pp = p + ((size_t)b * NP + n) * 3;
      float qc = (lane == 0) ? qx : ((lane == 1) ? qy : qz);
      xbuf[wv][kk][lane] = __fsub_rn(pp[lane], qc);
    }
    if (lane == 3) xbuf[wv][kk][67] = 0.0f;
  }
  __syncthreads();
  const float4* wr = (const float4*)(w1p + lane * 68);
  float4 wreg[17];
  #pragma unroll
  for (int c4 = 0; c4 < 17; ++c4) wreg[c4] = wr[c4];
  float ss = 0.f, qq = 0.f;
  for (int kk = 0; kk < KS; ++kk) {
    const float4* xr = (const float4*)(&xbuf[wv][kk][0]);
    float acc = 0.f;
    #pragma unroll
    for (int c4 = 0; c4 < 17; ++c4) {
      float4 w = wreg[c4]; float4 x = xr[c4];
      acc += w.x*x.x + w.y*x.y + w.z*x.z + w.w*x.w;
    }
    ss += acc; qq += acc * acc;
  }
  wbs[wv][lane] = ss; wbq[wv][lane] = qq;
  __syncthreads();
  if (threadIdx.x < 64) {
    float s  = wbs[0][threadIdx.x] + wbs[1][threadIdx.x] + wbs[2][threadIdx.x] + wbs[3][threadIdx.x];
    float s2 = wbq[0][threadIdx.x] + wbq[1][threadIdx.x] + wbq[2][threadIdx.x] + wbq[3][threadIdx.x];
    int slice = blockIdx.x & 63;
    atomicAdd(&stats1[(slice*2+0)*64 + threadIdx.x], s);
    atomicAdd(&stats1[(slice*2+1)*64 + threadIdx.x], s2);
  }
}

// ------------------------------------------------------------------
__global__ void fin1_kernel(const float* __restrict__ stats1,
                            const float* __restrict__ g, const float* __restrict__ bb,
                            float* __restrict__ sc) {
  int o = threadIdx.x;
  float s = 0.f, q = 0.f;
  for (int sl = 0; sl < 64; ++sl) { s += stats1[(sl*2+0)*64+o]; q += stats1[(sl*2+1)*64+o]; }
  const float cnt = (float)(BB * MQ * KS);
  float mean = s / cnt;
  float var = q / cnt - mean * mean;
  float rstd = 1.0f / sqrtf(var + 1e-5f);
  float gs = g[o] * rstd;
  sc[o] = gs;
  sc[64+o] = bb[o] - mean * gs;
}

__global__ void fin2_kernel(const float* __restrict__ stats2,
                            const float* __restrict__ g, const float* __restrict__ bb,
                            float* __restrict__ sc) {
  int o = threadIdx.x;
  float s = 0.f, q = 0.f;
  for (int sl = 0; sl < 64; ++sl) { s += stats2[(sl*2+0)*128+o]; q += stats2[(sl*2+1)*128+o]; }
  const float cnt = (float)(BB * MQ * KS);
  float mean = s / cnt;
  float var = q / cnt - mean * mean;
  float rstd = 1.0f / sqrtf(var + 1e-5f);
  float gs = g[o] * rstd;
  sc[o] = gs;
  sc[128+o] = bb[o] - mean * gs;
}

// ------------------------------------------------------------------
// P2: conv1 recompute, bn1+relu, conv2, stats2 + per-query max over K
// ------------------------------------------------------------------
__global__ __launch_bounds__(256) void p2_kernel(
    const float* __restrict__ p, const float* __restrict__ newp,
    const float* __restrict__ ft, const int* __restrict__ nidx,
    const float* __restrict__ w1p, const float* __restrict__ w2,
    const float* __restrict__ sc1,
    float* __restrict__ stats2, float* __restrict__ maxy2) {
  __shared__ __align__(16) float xbuf[4][KS][68];
  __shared__ float wbs[4][128], wbq[4][128];
  int wv = threadIdx.x >> 6, lane = threadIdx.x & 63;
  int qid = blockIdx.x * 4 + wv;
  int b = qid >> 11;
  int nv = (lane < KS) ? nidx[(size_t)qid * KS + lane] : 0;
  float qx = newp[qid*3], qy = newp[qid*3+1], qz = newp[qid*3+2];
  for (int kk = 0; kk < KS; ++kk) {
    int n = __shfl(nv, kk);
    const float* fr = ft + ((size_t)b * NP + n) * 64;
    xbuf[wv][kk][3 + lane] = fr[lane];
    if (lane < 3) {
      const float* pp = p + ((size_t)b * NP + n) * 3;
      float qc = (lane == 0) ? qx : ((lane == 1) ? qy : qz);
      xbuf[wv][kk][lane] = __fsub_rn(pp[lane], qc);
    }
    if (lane == 3) xbuf[wv][kk][67] = 0.0f;
  }
  __syncthreads();
  {
    const float4* wr = (const float4*)(w1p + lane * 68);
    float4 wreg[17];
    #pragma unroll
    for (int c4 = 0; c4 < 17; ++c4) wreg[c4] = wr[c4];
    float s1v = sc1[lane], t1v = sc1[64 + lane];
    for (int kk = 0; kk < KS; ++kk) {
      const float4* xr = (const float4*)(&xbuf[wv][kk][0]);
      float acc = 0.f;
      #pragma unroll
      for (int c4 = 0; c4 < 17; ++c4) {
        float4 w = wreg[c4]; float4 x = xr[c4];
        acc += w.x*x.x + w.y*x.y + w.z*x.z + w.w*x.w;
      }
      float h = fmaxf(0.0f, fmaf(acc, s1v, t1v));
      xbuf[wv][kk][lane] = h;
    }
  }
  const float4* w2a = (const float4*)(w2 + (size_t)lane * 64);
  const float4* w2b = (const float4*)(w2 + (size_t)(lane + 64) * 64);
  float4 wra[16], wrb[16];
  #pragma unroll
  for (int c4 = 0; c4 < 16; ++c4) { wra[c4] = w2a[c4]; wrb[c4] = w2b[c4]; }
  float ss0 = 0.f, qq0 = 0.f, mx0 = -INFINITY;
  float ss1 = 0.f, qq1 = 0.f, mx1 = -INFINITY;
  for (int kk = 0; kk < KS; ++kk) {
    const float4* hr = (const float4*)(&xbuf[wv][kk][0]);
    float a0 = 0.f, a1 = 0.f;
    #pragma unroll
    for (int c4 = 0; c4 < 16; ++c4) {
      float4 h4 = hr[c4];
      float4 wa = wra[c4]; float4 wb = wrb[c4];
      a0 += wa.x*h4.x + wa.y*h4.y + wa.z*h4.z + wa.w*h4.w;
      a1 += wb.x*h4.x + wb.y*h4.y + wb.z*h4.z + wb.w*h4.w;
    }
    ss0 += a0; qq0 += a0*a0; mx0 = fmaxf(mx0, a0);
    ss1 += a1; qq1 += a1*a1; mx1 = fmaxf(mx1, a1);
  }
  maxy2[(size_t)qid * 128 + lane] = mx0;
  maxy2[(size_t)qid * 128 + 64 + lane] = mx1;
  wbs[wv][lane] = ss0; wbs[wv][64+lane] = ss1;
  wbq[wv][lane] = qq0; wbq[wv][64+lane] = qq1;
  __syncthreads();
  if (threadIdx.x < 128) {
    float s  = wbs[0][threadIdx.x] + wbs[1][threadIdx.x] + wbs[2][threadIdx.x] + wbs[3][threadIdx.x];
    float s2 = wbq[0][threadIdx.x] + wbq[1][threadIdx.x] + wbq[2][threadIdx.x] + wbq[3][threadIdx.x];
    int slice = blockIdx.x & 63;
    atomicAdd(&stats2[(slice*2+0)*128 + threadIdx.x], s);
    atomicAdd(&stats2[(slice*2+1)*128 + threadIdx.x], s2);
  }
}

// ------------------------------------------------------------------
__global__ __launch_bounds__(256) void p3_kernel(
    const float* __restrict__ ft, const int* __restrict__ idx_i,
    const float* __restrict__ w_skip, const float* __restrict__ b_skip,
    const float* __restrict__ sc2, const float* __restrict__ maxy2,
    float* __restrict__ outf) {
  int wv = threadIdx.x >> 6, lane = threadIdx.x & 63;
  int qid = blockIdx.x * 4 + wv;
  int b = qid >> 11, m = qid & (MQ - 1);
  int n = idx_i[qid];
  const float4* f4 = (const float4*)(ft + ((size_t)b * NP + n) * 64);
  const float4* wa = (const float4*)(w_skip + (size_t)lane * 64);
  const float4* wb = (const float4*)(w_skip + (size_t)(lane + 64) * 64);
  float a0 = b_skip[lane], a1 = b_skip[lane + 64];
  #pragma unroll
  for (int c4 = 0; c4 < 16; ++c4) {
    float4 x = f4[c4]; float4 u = wa[c4]; float4 v = wb[c4];
    a0 += u.x*x.x + u.y*x.y + u.z*x.z + u.w*x.w;
    a1 += v.x*x.x + v.y*x.y + v.z*x.z + v.w*x.w;
  }
  float v0 = maxy2[(size_t)qid * 128 + lane];
  float v1 = maxy2[(size_t)qid * 128 + 64 + lane];
  float r0 = fmaxf(0.0f, fmaf(v0, sc2[lane],      sc2[128 + lane])      + a0);
  float r1 = fmaxf(0.0f, fmaf(v1, sc2[lane + 64], sc2[128 + lane + 64]) + a1);
  outf[((size_t)b * 128 + lane) * MQ + m] = r0;
  outf[((size_t)b * 128 + lane + 64) * MQ + m] = r1;
}

// ------------------------------------------------------------------
extern "C" void kernel_launch(void* const* d_in, const int* in_sizes, int n_in,
                              void* d_out, int out_size, void* d_ws, size_t ws_size,
                              hipStream_t stream) {
  (void)in_sizes; (void)n_in; (void)out_size; (void)ws_size;
  const float* p   = (const float*)d_in[0];
  const float* f   = (const float*)d_in[1];
  const float* w1  = (const float*)d_in[2];
  const float* g1  = (const float*)d_in[3];
  const float* b1  = (const float*)d_in[4];
  const float* w2  = (const float*)d_in[5];
  const float* g2  = (const float*)d_in[6];
  const float* b2  = (const float*)d_in[7];
  const float* wsk = (const float*)d_in[8];
  const float* bsk = (const float*)d_in[9];
  float* out = (float*)d_out;
  float* wsf = (float*)d_ws;

  float* ft    = wsf + WS_FT;
  int*   nidx  = (int*)(wsf + WS_NIDX);
  int*   idxi  = (int*)(wsf + WS_IDXI);
  float* st1   = wsf + WS_ST1;
  float* st2   = wsf + WS_ST2;
  float* sc1   = wsf + WS_SC1;
  float* sc2   = wsf + WS_SC2;
  float* maxy2 = wsf + WS_MAXY2;
  float* w1p   = wsf + WS_W1P;

  float* out_newp = out;
  float* out_f    = out + BB*MQ*3;

  (void)hipMemsetAsync(st1, 0, (8192 + 16384) * sizeof(float), stream);

  transpose_f_kernel<<<dim3(NP/64, BB), 256, 0, stream>>>(f, ft);
  prep_w1_kernel<<<17, 256, 0, stream>>>(w1, w1p);
  fps_kernel<<<BB, FPS_T, 0, stream>>>(p, out, idxi);
  ballq_kernel<<<BB*MQ/4, 256, 0, stream>>>(p, out_newp, nidx);
  p1_kernel<<<BB*MQ/4, 256, 0, stream>>>(p, out_newp, ft, nidx, w1p, st1);
  fin1_kernel<<<1, 64, 0, stream>>>(st1, g1, b1, sc1);
  p2_kernel<<<BB*MQ/4, 256, 0, stream>>>(p, out_newp, ft, nidx, w1p, w2, sc1, st2, maxy2);
  fin2_kernel<<<1, 128, 0, stream>>>(st2, g2, b2, sc2);
  p3_kernel<<<BB*MQ/4, 256, 0, stream>>>(ft, idxi, wsk, bsk, sc2, maxy2, out_f);
}